// Round 10
// baseline (712.168 us; speedup 1.0000x reference)
//
#include <hip/hip_runtime.h>
#include <hip/hip_bf16.h>

#define V_ 50257
#define H_ 1024
#define S_ 2048

typedef float f32x4 __attribute__((ext_vector_type(4)));
typedef short s16x8 __attribute__((ext_vector_type(8)));

__device__ __forceinline__ unsigned short f2bf(float f){
  unsigned u = __builtin_bit_cast(unsigned, f);
  return (unsigned short)((u + 0x7FFFu + ((u >> 16) & 1u)) >> 16);
}
__device__ __forceinline__ unsigned cvt2(float a, float b){
  return (unsigned)f2bf(a) | ((unsigned)f2bf(b) << 16);
}
__device__ __forceinline__ float bf2f(unsigned short h){
  return __builtin_bit_cast(float, (unsigned)h << 16);
}
__device__ __forceinline__ float fast_tanh(float x){
  return 1.0f - 2.0f/(__expf(2.0f*x)+1.0f);
}
__device__ __forceinline__ float fast_sig(float x){
  return 1.0f/(1.0f+__expf(-x));
}
__device__ __forceinline__ void gld_lds16(const void* g, void* l){
  __builtin_amdgcn_global_load_lds((const __attribute__((address_space(1))) void*)g,
                                   (__attribute__((address_space(3))) void*)l, 16, 0, 0);
}

#define BAR() do { __builtin_amdgcn_sched_barrier(0); __builtin_amdgcn_s_barrier(); __builtin_amdgcn_sched_barrier(0); } while(0)
#define VMW4() asm volatile("s_waitcnt vmcnt(4)" ::: "memory")
#define VMW0() asm volatile("s_waitcnt vmcnt(0)" ::: "memory")

// ---- convert f32 -> bf16, small (Ua_w) ----
__global__ __launch_bounds__(256) void k_cvt_bf16(const float* __restrict__ src,
                                                  unsigned short* __restrict__ dst, int n){
  int i = (blockIdx.x*256 + threadIdx.x)*4;
  if (i < n){
    float4 f = *(const float4*)(src + i);
    uint2 u;
    u.x = cvt2(f.x, f.y);
    u.y = cvt2(f.z, f.w);
    *(uint2*)(dst + i) = u;
  }
}

// ---- convert enc (134217728 f32) -> bf16, grid-stride ----
__global__ __launch_bounds__(256) void k_cvt_enc(const float* __restrict__ src,
                                                 unsigned short* __restrict__ dst){
  const size_t stride = (size_t)gridDim.x * 256;
  const float4* s4 = (const float4*)src;
  uint2* d2 = (uint2*)dst;
  for (size_t i = (size_t)blockIdx.x*256 + threadIdx.x; i < 33554432u; i += stride){
    float4 f = s4[i];
    uint2 u;
    u.x = cvt2(f.x, f.y);
    u.y = cvt2(f.z, f.w);
    d2[i] = u;
  }
}

// ---- 256x256 proje GEMM, 16 waves x 64x64 (4 waves/SIMD) ----
// A: enc_bf [131072][1024]; B: ua_bf [1024][1024]; BK=64, 1024 thr (4M x 4N waves).
// LDS (dynamic 128KB): A[2][256][64] | B[2][256][64] bf16, chunk-XOR swizzled.
__global__ __launch_bounds__(1024,4) void k_proje256(
    const unsigned short* __restrict__ A,
    const unsigned short* __restrict__ Bw,
    const float* __restrict__ ps,
    const float* __restrict__ Ua_b,
    const float* __restrict__ va,
    float* __restrict__ part)
{
  extern __shared__ unsigned short smem[];   // [0..32767]=A slots, [32768..65535]=B slots
  const int t = threadIdx.x;
  const int lane = t & 63, wid = t >> 6;     // wid 0..15
  const int lr = lane & 15, lk = lane >> 4;
  const int wr = wid >> 2, wc = wid & 3;     // 4M x 4N wave grid, 64x64 tiles

  int bid = blockIdx.x;
  int L = (bid & 7) * 256 + (bid >> 3);      // XCD-chunked swizzle (2048 % 8 == 0)
  const int wgm = L >> 2, wgn = L & 3;
  const int m0 = wgm * 256, n0 = wgn * 256;

  const int srow = lane >> 3;                // 0..7
  const int schunk = (lane & 7) ^ srow;      // inverse swizzle on SOURCE

  f32x4 acc[4][4] = {};
  s16x8 af[4], bfr[4];

  // stage one K-tile (A 32KB + B 32KB) with 4 gld_lds per thread
  auto STAGE = [&](int slot, int kt){
    #pragma unroll
    for (int h = 0; h < 4; ++h){
      const unsigned short* gsrc = (h < 2) ? A : Bw;
      const size_t g0 = (h < 2) ? (size_t)m0 : (size_t)n0;
      unsigned short* ldst = smem + ((h < 2) ? 0 : 32768) + slot*16384;
      int rb = (h & 1)*128 + wid*8;          // wave-uniform row base
      gld_lds16(gsrc + (g0 + rb + srow)*1024 + kt*64 + schunk*8,
                ldst + rb*64);
    }
  };

#define SUBPH(As_, Bs_, ks) do { \
    _Pragma("unroll") \
    for (int ni = 0; ni < 4; ++ni){ \
      int rl = wc*64 + ni*16 + lr; \
      bfr[ni] = *(const s16x8*)((Bs_) + rl*64 + ((((ks)*4+lk) ^ (lr&7))*8)); \
    } \
    _Pragma("unroll") \
    for (int mi = 0; mi < 4; ++mi){ \
      int rl = wr*64 + mi*16 + lr; \
      af[mi] = *(const s16x8*)((As_) + rl*64 + ((((ks)*4+lk) ^ (lr&7))*8)); \
    } \
    __builtin_amdgcn_s_setprio(1); \
    _Pragma("unroll") \
    for (int mi = 0; mi < 4; ++mi) \
      _Pragma("unroll") \
      for (int ni = 0; ni < 4; ++ni) \
        acc[mi][ni] = __builtin_amdgcn_mfma_f32_16x16x32_bf16(af[mi], bfr[ni], acc[mi][ni], 0,0,0); \
    __builtin_amdgcn_s_setprio(0); \
  } while(0)

#define HALF(slot) do { \
    const unsigned short* As_ = smem + (slot)*16384; \
    const unsigned short* Bs_ = smem + 32768 + (slot)*16384; \
    SUBPH(As_, Bs_, 0); \
    SUBPH(As_, Bs_, 1); \
  } while(0)

  // prologue: stage tiles 0,1; wait tile0 landed (4 left in flight)
  STAGE(0, 0);
  STAGE(1, 1);
  VMW4(); BAR();

  for (int i = 0; i < 8; ++i){
    HALF(0);                       // compute K-tile 2i
    if (i < 7){
      BAR();                       // all reads of slot0 done
      STAGE(0, 2*i + 2);           // prefetch tile 2i+2
      VMW4();                      // tile 2i+1 landed (2i+2's 4 still in flight)
      BAR();
    } else {
      VMW0();                      // tail: tile 15 landed
      BAR();
    }
    HALF(1);                       // compute K-tile 2i+1
    if (i < 7){
      BAR();
      STAGE(1, 2*i + 3);           // prefetch tile 2i+3
      VMW4();                      // tile 2i+2 landed
      BAR();
    }
  }

  // epilogue: tanh + va-weighted reduce over this wave's 64-col strip
  const int b = m0 >> 11;          // S = 2048
  float psv[4], vav[4];
  #pragma unroll
  for (int ni = 0; ni < 4; ++ni){
    int n = n0 + wc*64 + ni*16 + lr;
    psv[ni] = ps[b*1024 + n] + Ua_b[n];
    vav[ni] = va[n];
  }
  #pragma unroll
  for (int mi = 0; mi < 4; ++mi){
    float p0=0.f,p1=0.f,p2=0.f,p3=0.f;
    #pragma unroll
    for (int ni = 0; ni < 4; ++ni){
      p0 += vav[ni]*fast_tanh(acc[mi][ni][0] + psv[ni]);
      p1 += vav[ni]*fast_tanh(acc[mi][ni][1] + psv[ni]);
      p2 += vav[ni]*fast_tanh(acc[mi][ni][2] + psv[ni]);
      p3 += vav[ni]*fast_tanh(acc[mi][ni][3] + psv[ni]);
    }
    #pragma unroll
    for (int off = 1; off < 16; off <<= 1){
      p0 += __shfl_xor(p0, off);
      p1 += __shfl_xor(p1, off);
      p2 += __shfl_xor(p2, off);
      p3 += __shfl_xor(p3, off);
    }
    if (lr == 0){
      int rg = m0 + wr*64 + mi*16 + lk*4;
      int slot = wgn*4 + wc;
      part[(size_t)rg*16 + slot]     = p0;
      part[(size_t)(rg+1)*16 + slot] = p1;
      part[(size_t)(rg+2)*16 + slot] = p2;
      part[(size_t)(rg+3)*16 + slot] = p3;
    }
  }
#undef SUBPH
#undef HALF
}

// ---- fallback f32-staging proje (used only if ws too small for enc_bf) ----
__global__ __launch_bounds__(256,2) void k_proje_f32(
    const float* __restrict__ A,
    const unsigned short* __restrict__ Bw,
    const float* __restrict__ ps,
    const float* __restrict__ Ua_b,
    const float* __restrict__ va,
    float* __restrict__ part)
{
  __shared__ unsigned char sm[32768];
  const int t = threadIdx.x;
  const int lane = t & 63, wid = t >> 6;
  const int lr = lane & 15, lk = lane >> 4;
  int bid = blockIdx.x;
  int L = (bid & 7) * 1024 + (bid >> 3);
  const int wgm = L >> 3, wgn = L & 7;
  const int m0 = wgm * 128, n0 = wgn * 128;
  const int wm = wid >> 1, wn = wid & 1;

  f32x4 acc[4][4] = {};
  const int row2 = t >> 1, half = t & 1;
  const float* aSrc = A + (size_t)(m0 + row2) * 1024 + half * 32;
  const unsigned short* bSrc = Bw + (size_t)(n0 + row2) * 1024 + half * 32;
  unsigned char* Al = sm;
  unsigned char* Bl = sm + 16384;
  const int swzr = row2 & 7;

  for (int kt = 0; kt < 16; ++kt){
    __syncthreads();
    #pragma unroll
    for (int c = 0; c < 4; ++c){
      float4 f0 = *(const float4*)(aSrc + kt*64 + c*8);
      float4 f1 = *(const float4*)(aSrc + kt*64 + c*8 + 4);
      union { unsigned u[4]; s16x8 v; } p;
      p.u[0]=cvt2(f0.x,f0.y); p.u[1]=cvt2(f0.z,f0.w);
      p.u[2]=cvt2(f1.x,f1.y); p.u[3]=cvt2(f1.z,f1.w);
      int ch = half*4 + c;
      *(s16x8*)(Al + row2*128 + ((ch ^ swzr)*16)) = p.v;
    }
    #pragma unroll
    for (int c = 0; c < 4; ++c){
      s16x8 v = *(const s16x8*)(bSrc + kt*64 + (half*4 + c)*8);
      *(s16x8*)(Bl + row2*128 + (((half*4+c) ^ swzr)*16)) = v;
    }
    __syncthreads();
    #pragma unroll
    for (int ks = 0; ks < 2; ++ks){
      s16x8 af[4], bfr[4];
      #pragma unroll
      for (int mi = 0; mi < 4; ++mi){
        int r = wm*64 + mi*16 + lr;
        af[mi] = *(const s16x8*)(Al + r*128 + (((ks*4+lk) ^ (lr&7))*16));
      }
      #pragma unroll
      for (int ni = 0; ni < 4; ++ni){
        int r = wn*64 + ni*16 + lr;
        bfr[ni] = *(const s16x8*)(Bl + r*128 + (((ks*4+lk) ^ (lr&7))*16));
      }
      #pragma unroll
      for (int mi = 0; mi < 4; ++mi)
        #pragma unroll
        for (int ni = 0; ni < 4; ++ni)
          acc[mi][ni] = __builtin_amdgcn_mfma_f32_16x16x32_bf16(af[mi], bfr[ni], acc[mi][ni], 0,0,0);
    }
  }
  const int b = m0 >> 11;
  float psv[4], vav[4];
  #pragma unroll
  for (int ni = 0; ni < 4; ++ni){
    int n = n0 + wn*64 + ni*16 + lr;
    psv[ni] = ps[b*1024 + n] + Ua_b[n];
    vav[ni] = va[n];
  }
  #pragma unroll
  for (int mi = 0; mi < 4; ++mi){
    float p0=0.f,p1=0.f,p2=0.f,p3=0.f;
    #pragma unroll
    for (int ni = 0; ni < 4; ++ni){
      p0 += vav[ni]*fast_tanh(acc[mi][ni][0] + psv[ni]);
      p1 += vav[ni]*fast_tanh(acc[mi][ni][1] + psv[ni]);
      p2 += vav[ni]*fast_tanh(acc[mi][ni][2] + psv[ni]);
      p3 += vav[ni]*fast_tanh(acc[mi][ni][3] + psv[ni]);
    }
    #pragma unroll
    for (int off = 1; off < 16; off <<= 1){
      p0 += __shfl_xor(p0, off);
      p1 += __shfl_xor(p1, off);
      p2 += __shfl_xor(p2, off);
      p3 += __shfl_xor(p3, off);
    }
    if (lr == 0){
      int rg = m0 + wm*64 + mi*16 + lk*4;
      int slot = wgn*2 + wn;
      part[(size_t)rg*16 + slot]     = p0;
      part[(size_t)(rg+1)*16 + slot] = p1;
      part[(size_t)(rg+2)*16 + slot] = p2;
      part[(size_t)(rg+3)*16 + slot] = p3;
    }
  }
}

// ---- skinny GEMM: C(64 x N) = A(64 x K) @ [B1|B2]^T + bias1 + bias2 ----
__global__ __launch_bounds__(256,2) void k_gemm64(
    const float* __restrict__ A,
    const float* __restrict__ B1,
    const float* __restrict__ B2,
    const float* __restrict__ bias1,
    const float* __restrict__ bias2,
    float* __restrict__ C, int ldC,
    int N, int K, int K1)
{
  __shared__ unsigned char sm[16384];
  const int t = threadIdx.x;
  const int lane = t & 63, wid = t >> 6;
  const int lr = lane & 15, lk = lane >> 4;
  const int n0 = blockIdx.x * 64;
  f32x4 acc[4] = {};
  const int row = t >> 2, seg = t & 3;
  unsigned char* Al = sm;
  unsigned char* Bl = sm + 8192;
  const int swzr = row & 7;
  const int K2 = K - K1;

  for (int k0 = 0; k0 < K; k0 += 64){
    __syncthreads();
    {
      const float* s = A + (size_t)row*K + k0 + seg*16;
      #pragma unroll
      for (int c = 0; c < 2; ++c){
        float4 f0 = *(const float4*)(s + c*8);
        float4 f1 = *(const float4*)(s + c*8 + 4);
        union { unsigned u[4]; s16x8 v; } p;
        p.u[0]=cvt2(f0.x,f0.y); p.u[1]=cvt2(f0.z,f0.w);
        p.u[2]=cvt2(f1.x,f1.y); p.u[3]=cvt2(f1.z,f1.w);
        *(s16x8*)(Al + row*128 + (((seg*2+c) ^ swzr)*16)) = p.v;
      }
    }
    {
      int n = n0 + row;
      #pragma unroll
      for (int c = 0; c < 2; ++c){
        union { unsigned u[4]; s16x8 v; } p;
        if (n < N){
          int k = k0 + seg*16 + c*8;
          const float* s;
          if (k < K1) s = B1 + (size_t)n*K1 + k;
          else        s = B2 + (size_t)n*K2 + (k - K1);
          float4 f0 = *(const float4*)(s);
          float4 f1 = *(const float4*)(s + 4);
          p.u[0]=cvt2(f0.x,f0.y); p.u[1]=cvt2(f0.z,f0.w);
          p.u[2]=cvt2(f1.x,f1.y); p.u[3]=cvt2(f1.z,f1.w);
        } else {
          p.u[0]=0u; p.u[1]=0u; p.u[2]=0u; p.u[3]=0u;
        }
        *(s16x8*)(Bl + row*128 + (((seg*2+c) ^ swzr)*16)) = p.v;
      }
    }
    __syncthreads();
    #pragma unroll
    for (int ks = 0; ks < 2; ++ks){
      s16x8 bfr = *(const s16x8*)(Bl + (wid*16+lr)*128 + (((ks*4+lk) ^ (lr&7))*16));
      #pragma unroll
      for (int mi = 0; mi < 4; ++mi){
        s16x8 af = *(const s16x8*)(Al + (mi*16+lr)*128 + (((ks*4+lk) ^ (lr&7))*16));
        acc[mi] = __builtin_amdgcn_mfma_f32_16x16x32_bf16(af, bfr, acc[mi], 0,0,0);
      }
    }
  }
  int n = n0 + wid*16 + lr;
  if (n < N){
    float bv = (bias1 ? bias1[n] : 0.f) + (bias2 ? bias2[n] : 0.f);
    #pragma unroll
    for (int mi = 0; mi < 4; ++mi){
      #pragma unroll
      for (int r = 0; r < 4; ++r){
        C[(size_t)(mi*16 + lk*4 + r)*ldC + n] = acc[mi][r] + bv;
      }
    }
  }
}

// ---- FC: out[b][v] = h[b,:]·fc_w[v,:] + fc_b[v]; barrier-free MFMA streamer ----
// grid 786 x 256thr; wave = 16 v-rows x full 64 batch (16 VGPR acc -> high occupancy).
__global__ __launch_bounds__(256) void k_fc(
    const unsigned short* __restrict__ hbf,
    const float* __restrict__ fcw,
    const float* __restrict__ fcb,
    float* __restrict__ out)
{
  const int t = threadIdx.x;
  const int lane = t & 63, wid = t >> 6;
  const int lr = lane & 15, lk = lane >> 4;
  const int v = blockIdx.x*64 + wid*16 + lr;   // this lane's v-row
  const bool vok = v < V_;
  f32x4 acc[4] = {};                           // [mi] batch tiles

  for (int kt = 0; kt < 32; ++kt){
    s16x8 afr[4];
    #pragma unroll
    for (int mi = 0; mi < 4; ++mi)
      afr[mi] = *(const s16x8*)(hbf + (size_t)(mi*16 + lr)*1024 + kt*32 + lk*8);
    union { unsigned u[4]; s16x8 w; } p;
    if (vok){
      const float* s = fcw + (size_t)v*1024 + kt*32 + lk*8;
      float4 f0 = *(const float4*)(s);
      float4 f1 = *(const float4*)(s + 4);
      p.u[0]=cvt2(f0.x,f0.y); p.u[1]=cvt2(f0.z,f0.w);
      p.u[2]=cvt2(f1.x,f1.y); p.u[3]=cvt2(f1.z,f1.w);
    } else {
      p.u[0]=0u; p.u[1]=0u; p.u[2]=0u; p.u[3]=0u;
    }
    #pragma unroll
    for (int mi = 0; mi < 4; ++mi)
      acc[mi] = __builtin_amdgcn_mfma_f32_16x16x32_bf16(afr[mi], p.w, acc[mi], 0,0,0);
  }
  if (vok){
    float bv = fcb[v];
    #pragma unroll
    for (int mi = 0; mi < 4; ++mi){
      #pragma unroll
      for (int r = 0; r < 4; ++r){
        out[(size_t)(mi*16 + lk*4 + r)*V_ + v] = acc[mi][r] + bv;
      }
    }
  }
}

// ---- softmax over S per batch ----
__global__ __launch_bounds__(256) void k_softmax(const float* __restrict__ part,
                                                 const float* __restrict__ va_b,
                                                 float* __restrict__ attn){
  __shared__ float sc[2048];
  __shared__ float red[8];
  const int b = blockIdx.x, t = threadIdx.x;
  float vb = va_b[0];
  float lmax = -1e30f;
  #pragma unroll
  for (int j = 0; j < 8; ++j){
    int s = t + j*256;
    const float* p = part + ((size_t)b*2048 + s)*16;
    float v = vb;
    #pragma unroll
    for (int i = 0; i < 16; ++i) v += p[i];
    sc[s] = v;
    lmax = fmaxf(lmax, v);
  }
  for (int off = 32; off; off >>= 1) lmax = fmaxf(lmax, __shfl_xor(lmax, off));
  if ((t&63)==0) red[t>>6] = lmax;
  __syncthreads();
  float m = fmaxf(fmaxf(red[0],red[1]),fmaxf(red[2],red[3]));
  float lsum = 0.f;
  #pragma unroll
  for (int j = 0; j < 8; ++j){
    int s = t + j*256;
    float e = __expf(sc[s]-m);
    sc[s] = e; lsum += e;
  }
  for (int off = 32; off; off >>= 1) lsum += __shfl_xor(lsum, off);
  if ((t&63)==0) red[4 + (t>>6)] = lsum;
  __syncthreads();
  float inv = 1.f/(red[4]+red[5]+red[6]+red[7]);
  #pragma unroll
  for (int j = 0; j < 8; ++j){
    int s = t + j*256;
    attn[(size_t)b*2048+s] = sc[s]*inv;
  }
}

// ---- context partials from bf16 enc: 16 chunks of 128 ----
__global__ __launch_bounds__(256) void k_context_bf(const float* __restrict__ attn,
                                                    const unsigned short* __restrict__ encb,
                                                    float* __restrict__ ctxp){
  const int b = blockIdx.x >> 4, scid = blockIdx.x & 15;
  const int t = threadIdx.x;
  float a0=0.f,a1=0.f,a2=0.f,a3=0.f;
  const unsigned short* e = encb + ((size_t)b*2048 + scid*128)*1024 + t*4;
  const float* at = attn + (size_t)b*2048 + scid*128;
  #pragma unroll 4
  for (int s = 0; s < 128; ++s){
    float a = at[s];
    ushort4 v = *(const ushort4*)(e + (size_t)s*1024);
    a0 += a*bf2f(v.x); a1 += a*bf2f(v.y); a2 += a*bf2f(v.z); a3 += a*bf2f(v.w);
  }
  float4 o; o.x=a0; o.y=a1; o.z=a2; o.w=a3;
  *(float4*)(ctxp + ((size_t)scid*64 + b)*1024 + t*4) = o;
}

// ---- context partials from f32 enc (fallback), 16 chunks ----
__global__ __launch_bounds__(256) void k_context_f32(const float* __restrict__ attn,
                                                     const float* __restrict__ enc,
                                                     float* __restrict__ ctxp){
  const int b = blockIdx.x >> 4, scid = blockIdx.x & 15;
  const int t = threadIdx.x;
  float a0=0.f,a1=0.f,a2=0.f,a3=0.f;
  const float* e = enc + ((size_t)b*2048 + scid*128)*1024;
  const float* at = attn + (size_t)b*2048 + scid*128;
  for (int s = 0; s < 128; ++s){
    float a = at[s];
    const float* er = e + (size_t)s*1024;
    a0 += a*er[t]; a1 += a*er[t+256]; a2 += a*er[t+512]; a3 += a*er[t+768];
  }
  float* o = ctxp + ((size_t)scid*64 + b)*1024;
  o[t]=a0; o[t+256]=a1; o[t+512]=a2; o[t+768]=a3;
}

// ---- build lstm_full [64][2560] = [emb gather | ctx reduce(16) | hidden] ----
__global__ __launch_bounds__(256) void k_build(const int* __restrict__ x,
                                               const float* __restrict__ emb,
                                               const float* __restrict__ ctxp,
                                               const float* __restrict__ hidden,
                                               float* __restrict__ lstm){
  const int b = blockIdx.x, t = threadIdx.x;
  int xe = x[b];
  for (int col = t; col < 2560; col += 256){
    float v;
    if (col < 512) v = emb[(size_t)xe*512 + col];
    else if (col < 1536){
      int h = col - 512;
      v = 0.f;
      #pragma unroll
      for (int i = 0; i < 16; ++i) v += ctxp[((size_t)i*64 + b)*1024 + h];
    } else v = hidden[(size_t)b*1024 + (col-1536)];
    lstm[(size_t)b*2560 + col] = v;
  }
}

// ---- LSTM pointwise (+ bf16 copy of h_new for FC) ----
__global__ __launch_bounds__(256) void k_lstm(const float* __restrict__ gates,
                                              const float* __restrict__ cell,
                                              float* __restrict__ out,
                                              unsigned short* __restrict__ hbf){
  int idx = blockIdx.x*256 + threadIdx.x;  // 0..65535
  int b = idx >> 10, h = idx & 1023;
  const float* g = gates + (size_t)b*4096;
  float gi = fast_sig(g[h]);
  float gf = fast_sig(g[h+1024]);
  float gg = fast_tanh(g[h+2048]);
  float go = fast_sig(g[h+3072]);
  float c  = gf*cell[idx] + gi*gg;
  float hn = go*fast_tanh(c);
  out[(size_t)V_*64 + idx]         = hn;   // h_new
  out[(size_t)V_*64 + 65536 + idx] = c;    // c_new
  hbf[idx] = f2bf(hn);
}

extern "C" void kernel_launch(void* const* d_in, const int* in_sizes, int n_in,
                              void* d_out, int out_size, void* d_ws, size_t ws_size,
                              hipStream_t stream){
  const int*   x     = (const int*)d_in[0];
  const float* hidden= (const float*)d_in[1];
  const float* cell  = (const float*)d_in[2];
  const float* enc   = (const float*)d_in[3];
  const float* emb   = (const float*)d_in[4];
  const float* Wa_w  = (const float*)d_in[5];
  const float* Wa_b  = (const float*)d_in[6];
  const float* Ua_w  = (const float*)d_in[7];
  const float* Ua_b  = (const float*)d_in[8];
  const float* va_w  = (const float*)d_in[9];
  const float* va_b  = (const float*)d_in[10];
  const float* Wih   = (const float*)d_in[11];
  const float* Whh   = (const float*)d_in[12];
  const float* bih   = (const float*)d_in[13];
  const float* bhh   = (const float*)d_in[14];
  const float* fc_w  = (const float*)d_in[15];
  const float* fc_b  = (const float*)d_in[16];
  float* out = (float*)d_out;
  char* ws = (char*)d_ws;
  unsigned short* ua_bf = (unsigned short*)(ws + 0);        // 2 MB
  float* ps    = (float*)(ws + 2097152);                    // 256 KB
  float* attn  = (float*)(ws + 2359296);                    // 512 KB
  float* lstm  = (float*)(ws + 2883584);                    // 640 KB
  float* gates = (float*)(ws + 3538944);                    // 1 MB
  float* part  = (float*)(ws + 6684672);                    // 8 MB [6684672, 15073280)
  // ctxp aliases part's upper half: part is dead after k_softmax, before k_context runs
  float* ctxp  = (float*)(ws + 10878976);                   // 4 MB [10878976, 15073280)
  unsigned short* h_bf = (unsigned short*)(ws + 15073280);  // 128 KB
  unsigned short* enc_bf = (unsigned short*)(ws + 16777216);// 256 MB
  const size_t REQ = 16777216u + 268435456u;

  hipLaunchKernelGGL(k_cvt_bf16, dim3(1024), dim3(256), 0, stream, Ua_w, ua_bf, 1048576);
  hipLaunchKernelGGL(k_gemm64, dim3(16), dim3(256), 0, stream,
                     hidden, Wa_w, nullptr, Wa_b, nullptr, ps, 1024, 1024, 1024, 1024);
  if (ws_size >= REQ){
    hipLaunchKernelGGL(k_cvt_enc, dim3(8192), dim3(256), 0, stream, enc, enc_bf);
    hipLaunchKernelGGL(k_proje256, dim3(2048), dim3(1024), 131072, stream,
                       enc_bf, ua_bf, ps, Ua_b, va_w, part);
    hipLaunchKernelGGL(k_softmax, dim3(64), dim3(256), 0, stream, part, va_b, attn);
    hipLaunchKernelGGL(k_context_bf, dim3(1024), dim3(256), 0, stream, attn, enc_bf, ctxp);
  } else {
    hipLaunchKernelGGL(k_proje_f32, dim3(8192), dim3(256), 0, stream,
                       enc, ua_bf, ps, Ua_b, va_w, part);
    hipLaunchKernelGGL(k_softmax, dim3(64), dim3(256), 0, stream, part, va_b, attn);
    hipLaunchKernelGGL(k_context_f32, dim3(1024), dim3(256), 0, stream, attn, enc, ctxp);
  }
  hipLaunchKernelGGL(k_build, dim3(64), dim3(256), 0, stream, x, emb, ctxp, hidden, lstm);
  hipLaunchKernelGGL(k_gemm64, dim3(64), dim3(256), 0, stream,
                     lstm, Wih, Whh, bih, bhh, gates, 4096, 4096, 2560, 1536);
  hipLaunchKernelGGL(k_lstm, dim3(256), dim3(256), 0, stream, gates, cell, out, h_bf);
  hipLaunchKernelGGL(k_fc, dim3(786), dim3(256), 0, stream, h_bf, fc_w, fc_b, out);
}

// Round 11
// 661.880 us; speedup vs baseline: 1.0760x; 1.0760x over previous
//
#include <hip/hip_runtime.h>
#include <hip/hip_bf16.h>

#define V_ 50257
#define H_ 1024
#define S_ 2048

typedef float f32x4 __attribute__((ext_vector_type(4)));
typedef short s16x8 __attribute__((ext_vector_type(8)));

__device__ __forceinline__ unsigned short f2bf(float f){
  unsigned u = __builtin_bit_cast(unsigned, f);
  return (unsigned short)((u + 0x7FFFu + ((u >> 16) & 1u)) >> 16);
}
__device__ __forceinline__ unsigned cvt2(float a, float b){
  return (unsigned)f2bf(a) | ((unsigned)f2bf(b) << 16);
}
__device__ __forceinline__ float bf2f(unsigned short h){
  return __builtin_bit_cast(float, (unsigned)h << 16);
}
__device__ __forceinline__ float fast_tanh(float x){
  return 1.0f - 2.0f/(__expf(2.0f*x)+1.0f);
}
__device__ __forceinline__ float fast_sig(float x){
  return 1.0f/(1.0f+__expf(-x));
}
__device__ __forceinline__ void gld_lds16(const void* g, void* l){
  __builtin_amdgcn_global_load_lds((const __attribute__((address_space(1))) void*)g,
                                   (__attribute__((address_space(3))) void*)l, 16, 0, 0);
}

#define BAR() do { __builtin_amdgcn_sched_barrier(0); __builtin_amdgcn_s_barrier(); __builtin_amdgcn_sched_barrier(0); } while(0)
#define VMW4() asm volatile("s_waitcnt vmcnt(4)" ::: "memory")
#define VMW2() asm volatile("s_waitcnt vmcnt(2)" ::: "memory")
#define VMW0() asm volatile("s_waitcnt vmcnt(0)" ::: "memory")

// ---- convert f32 -> bf16, small (Ua_w) ----
__global__ __launch_bounds__(256) void k_cvt_bf16(const float* __restrict__ src,
                                                  unsigned short* __restrict__ dst, int n){
  int i = (blockIdx.x*256 + threadIdx.x)*4;
  if (i < n){
    float4 f = *(const float4*)(src + i);
    uint2 u;
    u.x = cvt2(f.x, f.y);
    u.y = cvt2(f.z, f.w);
    *(uint2*)(dst + i) = u;
  }
}

// ---- convert enc (134217728 f32) -> bf16, grid-stride ----
__global__ __launch_bounds__(256) void k_cvt_enc(const float* __restrict__ src,
                                                 unsigned short* __restrict__ dst){
  const size_t stride = (size_t)gridDim.x * 256;
  const float4* s4 = (const float4*)src;
  uint2* d2 = (uint2*)dst;
  for (size_t i = (size_t)blockIdx.x*256 + threadIdx.x; i < 33554432u; i += stride){
    float4 f = s4[i];
    uint2 u;
    u.x = cvt2(f.x, f.y);
    u.y = cvt2(f.z, f.w);
    d2[i] = u;
  }
}

// ---- 256x256 proje GEMM, 16 waves x 64x64, issue-interleaved staging ----
// A: enc_bf [131072][1024]; B: ua_bf [1024][1024]; BK=64, 1024 thr (4M x 4N waves).
// LDS (dynamic 128KB): A[2][256][64] | B[2][256][64] bf16, chunk-XOR swizzled.
// Steady state: slot0 landed, slot1 4-outstanding; slot0's next-tile loads are
// issued INSIDE slot1's compute phases; vmcnt never drains to 0 mid-loop.
__global__ __launch_bounds__(1024,4) void k_proje256(
    const unsigned short* __restrict__ A,
    const unsigned short* __restrict__ Bw,
    const float* __restrict__ ps,
    const float* __restrict__ Ua_b,
    const float* __restrict__ va,
    float* __restrict__ part)
{
  extern __shared__ unsigned short smem[];   // [0..32767]=A slots, [32768..65535]=B slots
  const int t = threadIdx.x;
  const int lane = t & 63, wid = t >> 6;     // wid 0..15
  const int lr = lane & 15, lk = lane >> 4;
  const int wr = wid >> 2, wc = wid & 3;     // 4M x 4N wave grid, 64x64 tiles

  int bid = blockIdx.x;
  int L = (bid & 7) * 256 + (bid >> 3);      // XCD-chunked swizzle (2048 % 8 == 0)
  const int wgm = L >> 2, wgn = L & 3;
  const int m0 = wgm * 256, n0 = wgn * 256;

  const int srow = lane >> 3;                // 0..7
  const int schunk = (lane & 7) ^ srow;      // inverse swizzle on SOURCE

  f32x4 acc[4][4] = {};
  s16x8 af[4], bfr[4];

  // stage the A-halves (2 loads/thread) of one K-tile
  auto STAGE_A = [&](int slot, int kt){
    #pragma unroll
    for (int h = 0; h < 2; ++h){
      unsigned short* ldst = smem + slot*16384;
      int rb = h*128 + wid*8;
      gld_lds16(A + (size_t)(m0 + rb + srow)*1024 + kt*64 + schunk*8,
                ldst + rb*64);
    }
  };
  // stage the B-halves (2 loads/thread) of one K-tile
  auto STAGE_B = [&](int slot, int kt){
    #pragma unroll
    for (int h = 0; h < 2; ++h){
      unsigned short* ldst = smem + 32768 + slot*16384;
      int rb = h*128 + wid*8;
      gld_lds16(Bw + (size_t)(n0 + rb + srow)*1024 + kt*64 + schunk*8,
                ldst + rb*64);
    }
  };

#define SUBPH(As_, Bs_, ks) do { \
    _Pragma("unroll") \
    for (int ni = 0; ni < 4; ++ni){ \
      int rl = wc*64 + ni*16 + lr; \
      bfr[ni] = *(const s16x8*)((Bs_) + rl*64 + ((((ks)*4+lk) ^ (lr&7))*8)); \
    } \
    _Pragma("unroll") \
    for (int mi = 0; mi < 4; ++mi){ \
      int rl = wr*64 + mi*16 + lr; \
      af[mi] = *(const s16x8*)((As_) + rl*64 + ((((ks)*4+lk) ^ (lr&7))*8)); \
    } \
    __builtin_amdgcn_s_setprio(1); \
    _Pragma("unroll") \
    for (int mi = 0; mi < 4; ++mi) \
      _Pragma("unroll") \
      for (int ni = 0; ni < 4; ++ni) \
        acc[mi][ni] = __builtin_amdgcn_mfma_f32_16x16x32_bf16(af[mi], bfr[ni], acc[mi][ni], 0,0,0); \
    __builtin_amdgcn_s_setprio(0); \
  } while(0)

  const unsigned short* As0 = smem;
  const unsigned short* Bs0 = smem + 32768;
  const unsigned short* As1 = smem + 16384;
  const unsigned short* Bs1 = smem + 32768 + 16384;

  // prologue: tile0 -> slot0 (4 loads), tile1 -> slot1 (4 loads)
  STAGE_A(0, 0); STAGE_B(0, 0);
  STAGE_A(1, 1); STAGE_B(1, 1);
  VMW4(); BAR();                 // tile0 landed+visible; tile1 4-outstanding

  for (int i = 0; i < 8; ++i){
    SUBPH(As0, Bs0, 0);          // compute K-tile 2i from slot0
    SUBPH(As0, Bs0, 1);
    BAR();                       // slot0 reads complete (all waves)
    if (i < 7){
      STAGE_A(0, 2*i + 2);       // 2 loads -> slot0 (now writable); outstanding 6
      VMW2(); BAR();             // tile 2i+1 landed (2 newer stay in flight)
      SUBPH(As1, Bs1, 0);        // compute K-tile 2i+1 ...
      STAGE_B(0, 2*i + 2);       // ... overlapped with slot0's B stage; outstanding 4
      SUBPH(As1, Bs1, 1);
      BAR();                     // slot1 reads complete
      STAGE_A(1, 2*i + 3);       // 4 loads -> slot1; outstanding 8
      STAGE_B(1, 2*i + 3);
      VMW4(); BAR();             // tile 2i+2 landed; tile 2i+3 4-outstanding
    } else {
      VMW0(); BAR();             // tail: tile 15 landed
      SUBPH(As1, Bs1, 0);
      SUBPH(As1, Bs1, 1);
    }
  }

  // epilogue: tanh + va-weighted reduce over this wave's 64-col strip
  const int b = m0 >> 11;        // S = 2048
  float psv[4], vav[4];
  #pragma unroll
  for (int ni = 0; ni < 4; ++ni){
    int n = n0 + wc*64 + ni*16 + lr;
    psv[ni] = ps[b*1024 + n] + Ua_b[n];
    vav[ni] = va[n];
  }
  #pragma unroll
  for (int mi = 0; mi < 4; ++mi){
    float p0=0.f,p1=0.f,p2=0.f,p3=0.f;
    #pragma unroll
    for (int ni = 0; ni < 4; ++ni){
      p0 += vav[ni]*fast_tanh(acc[mi][ni][0] + psv[ni]);
      p1 += vav[ni]*fast_tanh(acc[mi][ni][1] + psv[ni]);
      p2 += vav[ni]*fast_tanh(acc[mi][ni][2] + psv[ni]);
      p3 += vav[ni]*fast_tanh(acc[mi][ni][3] + psv[ni]);
    }
    #pragma unroll
    for (int off = 1; off < 16; off <<= 1){
      p0 += __shfl_xor(p0, off);
      p1 += __shfl_xor(p1, off);
      p2 += __shfl_xor(p2, off);
      p3 += __shfl_xor(p3, off);
    }
    if (lr == 0){
      int rg = m0 + wr*64 + mi*16 + lk*4;
      int slot = wgn*4 + wc;
      part[(size_t)rg*16 + slot]     = p0;
      part[(size_t)(rg+1)*16 + slot] = p1;
      part[(size_t)(rg+2)*16 + slot] = p2;
      part[(size_t)(rg+3)*16 + slot] = p3;
    }
  }
#undef SUBPH
}

// ---- fallback f32-staging proje (used only if ws too small for enc_bf) ----
__global__ __launch_bounds__(256,2) void k_proje_f32(
    const float* __restrict__ A,
    const unsigned short* __restrict__ Bw,
    const float* __restrict__ ps,
    const float* __restrict__ Ua_b,
    const float* __restrict__ va,
    float* __restrict__ part)
{
  __shared__ unsigned char sm[32768];
  const int t = threadIdx.x;
  const int lane = t & 63, wid = t >> 6;
  const int lr = lane & 15, lk = lane >> 4;
  int bid = blockIdx.x;
  int L = (bid & 7) * 1024 + (bid >> 3);
  const int wgm = L >> 3, wgn = L & 7;
  const int m0 = wgm * 128, n0 = wgn * 128;
  const int wm = wid >> 1, wn = wid & 1;

  f32x4 acc[4][4] = {};
  const int row2 = t >> 1, half = t & 1;
  const float* aSrc = A + (size_t)(m0 + row2) * 1024 + half * 32;
  const unsigned short* bSrc = Bw + (size_t)(n0 + row2) * 1024 + half * 32;
  unsigned char* Al = sm;
  unsigned char* Bl = sm + 16384;
  const int swzr = row2 & 7;

  for (int kt = 0; kt < 16; ++kt){
    __syncthreads();
    #pragma unroll
    for (int c = 0; c < 4; ++c){
      float4 f0 = *(const float4*)(aSrc + kt*64 + c*8);
      float4 f1 = *(const float4*)(aSrc + kt*64 + c*8 + 4);
      union { unsigned u[4]; s16x8 v; } p;
      p.u[0]=cvt2(f0.x,f0.y); p.u[1]=cvt2(f0.z,f0.w);
      p.u[2]=cvt2(f1.x,f1.y); p.u[3]=cvt2(f1.z,f1.w);
      int ch = half*4 + c;
      *(s16x8*)(Al + row2*128 + ((ch ^ swzr)*16)) = p.v;
    }
    #pragma unroll
    for (int c = 0; c < 4; ++c){
      s16x8 v = *(const s16x8*)(bSrc + kt*64 + (half*4 + c)*8);
      *(s16x8*)(Bl + row2*128 + (((half*4+c) ^ swzr)*16)) = v;
    }
    __syncthreads();
    #pragma unroll
    for (int ks = 0; ks < 2; ++ks){
      s16x8 af[4], bfr[4];
      #pragma unroll
      for (int mi = 0; mi < 4; ++mi){
        int r = wm*64 + mi*16 + lr;
        af[mi] = *(const s16x8*)(Al + r*128 + (((ks*4+lk) ^ (lr&7))*16));
      }
      #pragma unroll
      for (int ni = 0; ni < 4; ++ni){
        int r = wn*64 + ni*16 + lr;
        bfr[ni] = *(const s16x8*)(Bl + r*128 + (((ks*4+lk) ^ (lr&7))*16));
      }
      #pragma unroll
      for (int mi = 0; mi < 4; ++mi)
        #pragma unroll
        for (int ni = 0; ni < 4; ++ni)
          acc[mi][ni] = __builtin_amdgcn_mfma_f32_16x16x32_bf16(af[mi], bfr[ni], acc[mi][ni], 0,0,0);
    }
  }
  const int b = m0 >> 11;
  float psv[4], vav[4];
  #pragma unroll
  for (int ni = 0; ni < 4; ++ni){
    int n = n0 + wn*64 + ni*16 + lr;
    psv[ni] = ps[b*1024 + n] + Ua_b[n];
    vav[ni] = va[n];
  }
  #pragma unroll
  for (int mi = 0; mi < 4; ++mi){
    float p0=0.f,p1=0.f,p2=0.f,p3=0.f;
    #pragma unroll
    for (int ni = 0; ni < 4; ++ni){
      p0 += vav[ni]*fast_tanh(acc[mi][ni][0] + psv[ni]);
      p1 += vav[ni]*fast_tanh(acc[mi][ni][1] + psv[ni]);
      p2 += vav[ni]*fast_tanh(acc[mi][ni][2] + psv[ni]);
      p3 += vav[ni]*fast_tanh(acc[mi][ni][3] + psv[ni]);
    }
    #pragma unroll
    for (int off = 1; off < 16; off <<= 1){
      p0 += __shfl_xor(p0, off);
      p1 += __shfl_xor(p1, off);
      p2 += __shfl_xor(p2, off);
      p3 += __shfl_xor(p3, off);
    }
    if (lr == 0){
      int rg = m0 + wm*64 + mi*16 + lk*4;
      int slot = wgn*2 + wn;
      part[(size_t)rg*16 + slot]     = p0;
      part[(size_t)(rg+1)*16 + slot] = p1;
      part[(size_t)(rg+2)*16 + slot] = p2;
      part[(size_t)(rg+3)*16 + slot] = p3;
    }
  }
}

// ---- skinny GEMM: C(64 x N) = A(64 x K) @ [B1|B2]^T + bias1 + bias2 ----
__global__ __launch_bounds__(256,2) void k_gemm64(
    const float* __restrict__ A,
    const float* __restrict__ B1,
    const float* __restrict__ B2,
    const float* __restrict__ bias1,
    const float* __restrict__ bias2,
    float* __restrict__ C, int ldC,
    int N, int K, int K1)
{
  __shared__ unsigned char sm[16384];
  const int t = threadIdx.x;
  const int lane = t & 63, wid = t >> 6;
  const int lr = lane & 15, lk = lane >> 4;
  const int n0 = blockIdx.x * 64;
  f32x4 acc[4] = {};
  const int row = t >> 2, seg = t & 3;
  unsigned char* Al = sm;
  unsigned char* Bl = sm + 8192;
  const int swzr = row & 7;
  const int K2 = K - K1;

  for (int k0 = 0; k0 < K; k0 += 64){
    __syncthreads();
    {
      const float* s = A + (size_t)row*K + k0 + seg*16;
      #pragma unroll
      for (int c = 0; c < 2; ++c){
        float4 f0 = *(const float4*)(s + c*8);
        float4 f1 = *(const float4*)(s + c*8 + 4);
        union { unsigned u[4]; s16x8 v; } p;
        p.u[0]=cvt2(f0.x,f0.y); p.u[1]=cvt2(f0.z,f0.w);
        p.u[2]=cvt2(f1.x,f1.y); p.u[3]=cvt2(f1.z,f1.w);
        *(s16x8*)(Al + row*128 + (((seg*2+c) ^ swzr)*16)) = p.v;
      }
    }
    {
      int n = n0 + row;
      #pragma unroll
      for (int c = 0; c < 2; ++c){
        union { unsigned u[4]; s16x8 v; } p;
        if (n < N){
          int k = k0 + seg*16 + c*8;
          const float* s;
          if (k < K1) s = B1 + (size_t)n*K1 + k;
          else        s = B2 + (size_t)n*K2 + (k - K1);
          float4 f0 = *(const float4*)(s);
          float4 f1 = *(const float4*)(s + 4);
          p.u[0]=cvt2(f0.x,f0.y); p.u[1]=cvt2(f0.z,f0.w);
          p.u[2]=cvt2(f1.x,f1.y); p.u[3]=cvt2(f1.z,f1.w);
        } else {
          p.u[0]=0u; p.u[1]=0u; p.u[2]=0u; p.u[3]=0u;
        }
        *(s16x8*)(Bl + row*128 + (((seg*2+c) ^ swzr)*16)) = p.v;
      }
    }
    __syncthreads();
    #pragma unroll
    for (int ks = 0; ks < 2; ++ks){
      s16x8 bfr = *(const s16x8*)(Bl + (wid*16+lr)*128 + (((ks*4+lk) ^ (lr&7))*16));
      #pragma unroll
      for (int mi = 0; mi < 4; ++mi){
        s16x8 af = *(const s16x8*)(Al + (mi*16+lr)*128 + (((ks*4+lk) ^ (lr&7))*16));
        acc[mi] = __builtin_amdgcn_mfma_f32_16x16x32_bf16(af, bfr, acc[mi], 0,0,0);
      }
    }
  }
  int n = n0 + wid*16 + lr;
  if (n < N){
    float bv = (bias1 ? bias1[n] : 0.f) + (bias2 ? bias2[n] : 0.f);
    #pragma unroll
    for (int mi = 0; mi < 4; ++mi){
      #pragma unroll
      for (int r = 0; r < 4; ++r){
        C[(size_t)(mi*16 + lk*4 + r)*ldC + n] = acc[mi][r] + bv;
      }
    }
  }
}

// ---- softmax over S per batch ----
__global__ __launch_bounds__(256) void k_softmax(const float* __restrict__ part,
                                                 const float* __restrict__ va_b,
                                                 float* __restrict__ attn){
  __shared__ float sc[2048];
  __shared__ float red[8];
  const int b = blockIdx.x, t = threadIdx.x;
  float vb = va_b[0];
  float lmax = -1e30f;
  #pragma unroll
  for (int j = 0; j < 8; ++j){
    int s = t + j*256;
    const float* p = part + ((size_t)b*2048 + s)*16;
    float v = vb;
    #pragma unroll
    for (int i = 0; i < 16; ++i) v += p[i];
    sc[s] = v;
    lmax = fmaxf(lmax, v);
  }
  for (int off = 32; off; off >>= 1) lmax = fmaxf(lmax, __shfl_xor(lmax, off));
  if ((t&63)==0) red[t>>6] = lmax;
  __syncthreads();
  float m = fmaxf(fmaxf(red[0],red[1]),fmaxf(red[2],red[3]));
  float lsum = 0.f;
  #pragma unroll
  for (int j = 0; j < 8; ++j){
    int s = t + j*256;
    float e = __expf(sc[s]-m);
    sc[s] = e; lsum += e;
  }
  for (int off = 32; off; off >>= 1) lsum += __shfl_xor(lsum, off);
  if ((t&63)==0) red[4 + (t>>6)] = lsum;
  __syncthreads();
  float inv = 1.f/(red[4]+red[5]+red[6]+red[7]);
  #pragma unroll
  for (int j = 0; j < 8; ++j){
    int s = t + j*256;
    attn[(size_t)b*2048+s] = sc[s]*inv;
  }
}

// ---- context partials from bf16 enc: 16 chunks of 128 ----
__global__ __launch_bounds__(256) void k_context_bf(const float* __restrict__ attn,
                                                    const unsigned short* __restrict__ encb,
                                                    float* __restrict__ ctxp){
  const int b = blockIdx.x >> 4, scid = blockIdx.x & 15;
  const int t = threadIdx.x;
  float a0=0.f,a1=0.f,a2=0.f,a3=0.f;
  const unsigned short* e = encb + ((size_t)b*2048 + scid*128)*1024 + t*4;
  const float* at = attn + (size_t)b*2048 + scid*128;
  #pragma unroll 4
  for (int s = 0; s < 128; ++s){
    float a = at[s];
    ushort4 v = *(const ushort4*)(e + (size_t)s*1024);
    a0 += a*bf2f(v.x); a1 += a*bf2f(v.y); a2 += a*bf2f(v.z); a3 += a*bf2f(v.w);
  }
  float4 o; o.x=a0; o.y=a1; o.z=a2; o.w=a3;
  *(float4*)(ctxp + ((size_t)scid*64 + b)*1024 + t*4) = o;
}

// ---- context partials from f32 enc (fallback), 16 chunks ----
__global__ __launch_bounds__(256) void k_context_f32(const float* __restrict__ attn,
                                                     const float* __restrict__ enc,
                                                     float* __restrict__ ctxp){
  const int b = blockIdx.x >> 4, scid = blockIdx.x & 15;
  const int t = threadIdx.x;
  float a0=0.f,a1=0.f,a2=0.f,a3=0.f;
  const float* e = enc + ((size_t)b*2048 + scid*128)*1024;
  const float* at = attn + (size_t)b*2048 + scid*128;
  for (int s = 0; s < 128; ++s){
    float a = at[s];
    const float* er = e + (size_t)s*1024;
    a0 += a*er[t]; a1 += a*er[t+256]; a2 += a*er[t+512]; a3 += a*er[t+768];
  }
  float* o = ctxp + ((size_t)scid*64 + b)*1024;
  o[t]=a0; o[t+256]=a1; o[t+512]=a2; o[t+768]=a3;
}

// ---- build lstm_full [64][2560] = [emb gather | ctx reduce(16) | hidden] ----
__global__ __launch_bounds__(256) void k_build(const int* __restrict__ x,
                                               const float* __restrict__ emb,
                                               const float* __restrict__ ctxp,
                                               const float* __restrict__ hidden,
                                               float* __restrict__ lstm){
  const int b = blockIdx.x, t = threadIdx.x;
  int xe = x[b];
  for (int col = t; col < 2560; col += 256){
    float v;
    if (col < 512) v = emb[(size_t)xe*512 + col];
    else if (col < 1536){
      int h = col - 512;
      v = 0.f;
      #pragma unroll
      for (int i = 0; i < 16; ++i) v += ctxp[((size_t)i*64 + b)*1024 + h];
    } else v = hidden[(size_t)b*1024 + (col-1536)];
    lstm[(size_t)b*2560 + col] = v;
  }
}

// ---- LSTM pointwise ----
__global__ __launch_bounds__(256) void k_lstm(const float* __restrict__ gates,
                                              const float* __restrict__ cell,
                                              float* __restrict__ out){
  int idx = blockIdx.x*256 + threadIdx.x;  // 0..65535
  int b = idx >> 10, h = idx & 1023;
  const float* g = gates + (size_t)b*4096;
  float gi = fast_sig(g[h]);
  float gf = fast_sig(g[h+1024]);
  float gg = fast_tanh(g[h+2048]);
  float go = fast_sig(g[h+3072]);
  float c  = gf*cell[idx] + gi*gg;
  float hn = go*fast_tanh(c);
  out[(size_t)V_*64 + idx]         = hn;   // h_new
  out[(size_t)V_*64 + 65536 + idx] = c;    // c_new
}

extern "C" void kernel_launch(void* const* d_in, const int* in_sizes, int n_in,
                              void* d_out, int out_size, void* d_ws, size_t ws_size,
                              hipStream_t stream){
  const int*   x     = (const int*)d_in[0];
  const float* hidden= (const float*)d_in[1];
  const float* cell  = (const float*)d_in[2];
  const float* enc   = (const float*)d_in[3];
  const float* emb   = (const float*)d_in[4];
  const float* Wa_w  = (const float*)d_in[5];
  const float* Wa_b  = (const float*)d_in[6];
  const float* Ua_w  = (const float*)d_in[7];
  const float* Ua_b  = (const float*)d_in[8];
  const float* va_w  = (const float*)d_in[9];
  const float* va_b  = (const float*)d_in[10];
  const float* Wih   = (const float*)d_in[11];
  const float* Whh   = (const float*)d_in[12];
  const float* bih   = (const float*)d_in[13];
  const float* bhh   = (const float*)d_in[14];
  const float* fc_w  = (const float*)d_in[15];
  const float* fc_b  = (const float*)d_in[16];
  float* out = (float*)d_out;
  char* ws = (char*)d_ws;
  unsigned short* ua_bf = (unsigned short*)(ws + 0);        // 2 MB
  float* ps    = (float*)(ws + 2097152);                    // 256 KB
  float* attn  = (float*)(ws + 2359296);                    // 512 KB
  float* lstm  = (float*)(ws + 2883584);                    // 640 KB
  float* gates = (float*)(ws + 3538944);                    // 1 MB
  float* part  = (float*)(ws + 6684672);                    // 8 MB [6684672, 15073280)
  // ctxp aliases part's upper half: part is dead after k_softmax, before k_context runs
  float* ctxp  = (float*)(ws + 10878976);                   // 4 MB [10878976, 15073280)
  unsigned short* enc_bf = (unsigned short*)(ws + 16777216);// 256 MB
  const size_t REQ = 16777216u + 268435456u;

  hipLaunchKernelGGL(k_cvt_bf16, dim3(1024), dim3(256), 0, stream, Ua_w, ua_bf, 1048576);
  hipLaunchKernelGGL(k_gemm64, dim3(16), dim3(256), 0, stream,
                     hidden, Wa_w, nullptr, Wa_b, nullptr, ps, 1024, 1024, 1024, 1024);
  if (ws_size >= REQ){
    hipLaunchKernelGGL(k_cvt_enc, dim3(8192), dim3(256), 0, stream, enc, enc_bf);
    hipLaunchKernelGGL(k_proje256, dim3(2048), dim3(1024), 131072, stream,
                       enc_bf, ua_bf, ps, Ua_b, va_w, part);
    hipLaunchKernelGGL(k_softmax, dim3(64), dim3(256), 0, stream, part, va_b, attn);
    hipLaunchKernelGGL(k_context_bf, dim3(1024), dim3(256), 0, stream, attn, enc_bf, ctxp);
  } else {
    hipLaunchKernelGGL(k_proje_f32, dim3(8192), dim3(256), 0, stream,
                       enc, ua_bf, ps, Ua_b, va_w, part);
    hipLaunchKernelGGL(k_softmax, dim3(64), dim3(256), 0, stream, part, va_b, attn);
    hipLaunchKernelGGL(k_context_f32, dim3(1024), dim3(256), 0, stream, attn, enc, ctxp);
  }
  hipLaunchKernelGGL(k_build, dim3(64), dim3(256), 0, stream, x, emb, ctxp, hidden, lstm);
  hipLaunchKernelGGL(k_gemm64, dim3(64), dim3(256), 0, stream,
                     lstm, Wih, Whh, bih, bhh, gates, 4096, 4096, 2560, 1536);
  hipLaunchKernelGGL(k_lstm, dim3(256), dim3(256), 0, stream, gates, cell, out);
  hipLaunchKernelGGL(k_gemm64, dim3(786), dim3(256), 0, stream,
                     out + (size_t)V_*64, fc_w, nullptr, fc_b, nullptr, out, V_, V_, 1024, 1024);
}

// Round 12
// 642.423 us; speedup vs baseline: 1.1086x; 1.0303x over previous
//
#include <hip/hip_runtime.h>
#include <hip/hip_bf16.h>

#define V_ 50257
#define H_ 1024
#define S_ 2048

typedef float f32x4 __attribute__((ext_vector_type(4)));
typedef short s16x8 __attribute__((ext_vector_type(8)));

__device__ __forceinline__ unsigned short f2bf(float f){
  unsigned u = __builtin_bit_cast(unsigned, f);
  return (unsigned short)((u + 0x7FFFu + ((u >> 16) & 1u)) >> 16);
}
__device__ __forceinline__ unsigned cvt2(float a, float b){
  return (unsigned)f2bf(a) | ((unsigned)f2bf(b) << 16);
}
__device__ __forceinline__ float bf2f(unsigned short h){
  return __builtin_bit_cast(float, (unsigned)h << 16);
}
__device__ __forceinline__ float fast_tanh(float x){
  return 1.0f - 2.0f/(__expf(2.0f*x)+1.0f);
}
__device__ __forceinline__ float fast_sig(float x){
  return 1.0f/(1.0f+__expf(-x));
}
__device__ __forceinline__ void gld_lds16(const void* g, void* l){
  __builtin_amdgcn_global_load_lds((const __attribute__((address_space(1))) void*)g,
                                   (__attribute__((address_space(3))) void*)l, 16, 0, 0);
}

#define BAR() do { __builtin_amdgcn_sched_barrier(0); __builtin_amdgcn_s_barrier(); __builtin_amdgcn_sched_barrier(0); } while(0)
#define VMW4() asm volatile("s_waitcnt vmcnt(4)" ::: "memory")
#define VMW2() asm volatile("s_waitcnt vmcnt(2)" ::: "memory")
#define VMW0() asm volatile("s_waitcnt vmcnt(0)" ::: "memory")

// ---- convert f32 -> bf16, small (Ua_w) ----
__global__ __launch_bounds__(256) void k_cvt_bf16(const float* __restrict__ src,
                                                  unsigned short* __restrict__ dst, int n){
  int i = (blockIdx.x*256 + threadIdx.x)*4;
  if (i < n){
    float4 f = *(const float4*)(src + i);
    uint2 u;
    u.x = cvt2(f.x, f.y);
    u.y = cvt2(f.z, f.w);
    *(uint2*)(dst + i) = u;
  }
}

// ---- convert enc (134217728 f32) -> bf16, grid-stride ----
__global__ __launch_bounds__(256) void k_cvt_enc(const float* __restrict__ src,
                                                 unsigned short* __restrict__ dst){
  const size_t stride = (size_t)gridDim.x * 256;
  const float4* s4 = (const float4*)src;
  uint2* d2 = (uint2*)dst;
  for (size_t i = (size_t)blockIdx.x*256 + threadIdx.x; i < 33554432u; i += stride){
    float4 f = s4[i];
    uint2 u;
    u.x = cvt2(f.x, f.y);
    u.y = cvt2(f.z, f.w);
    d2[i] = u;
  }
}

// ---- 256x256 proje GEMM, 16 waves x 64x64, issue-interleaved staging (r11 best) ----
__global__ __launch_bounds__(1024,4) void k_proje256(
    const unsigned short* __restrict__ A,
    const unsigned short* __restrict__ Bw,
    const float* __restrict__ ps,
    const float* __restrict__ Ua_b,
    const float* __restrict__ va,
    float* __restrict__ part)
{
  extern __shared__ unsigned short smem[];   // [0..32767]=A slots, [32768..65535]=B slots
  const int t = threadIdx.x;
  const int lane = t & 63, wid = t >> 6;     // wid 0..15
  const int lr = lane & 15, lk = lane >> 4;
  const int wr = wid >> 2, wc = wid & 3;     // 4M x 4N wave grid, 64x64 tiles

  int bid = blockIdx.x;
  int L = (bid & 7) * 256 + (bid >> 3);      // XCD-chunked swizzle (2048 % 8 == 0)
  const int wgm = L >> 2, wgn = L & 3;
  const int m0 = wgm * 256, n0 = wgn * 256;

  const int srow = lane >> 3;                // 0..7
  const int schunk = (lane & 7) ^ srow;      // inverse swizzle on SOURCE

  f32x4 acc[4][4] = {};
  s16x8 af[4], bfr[4];

  auto STAGE_A = [&](int slot, int kt){
    #pragma unroll
    for (int h = 0; h < 2; ++h){
      unsigned short* ldst = smem + slot*16384;
      int rb = h*128 + wid*8;
      gld_lds16(A + (size_t)(m0 + rb + srow)*1024 + kt*64 + schunk*8,
                ldst + rb*64);
    }
  };
  auto STAGE_B = [&](int slot, int kt){
    #pragma unroll
    for (int h = 0; h < 2; ++h){
      unsigned short* ldst = smem + 32768 + slot*16384;
      int rb = h*128 + wid*8;
      gld_lds16(Bw + (size_t)(n0 + rb + srow)*1024 + kt*64 + schunk*8,
                ldst + rb*64);
    }
  };

#define SUBPH(As_, Bs_, ks) do { \
    _Pragma("unroll") \
    for (int ni = 0; ni < 4; ++ni){ \
      int rl = wc*64 + ni*16 + lr; \
      bfr[ni] = *(const s16x8*)((Bs_) + rl*64 + ((((ks)*4+lk) ^ (lr&7))*8)); \
    } \
    _Pragma("unroll") \
    for (int mi = 0; mi < 4; ++mi){ \
      int rl = wr*64 + mi*16 + lr; \
      af[mi] = *(const s16x8*)((As_) + rl*64 + ((((ks)*4+lk) ^ (lr&7))*8)); \
    } \
    __builtin_amdgcn_s_setprio(1); \
    _Pragma("unroll") \
    for (int mi = 0; mi < 4; ++mi) \
      _Pragma("unroll") \
      for (int ni = 0; ni < 4; ++ni) \
        acc[mi][ni] = __builtin_amdgcn_mfma_f32_16x16x32_bf16(af[mi], bfr[ni], acc[mi][ni], 0,0,0); \
    __builtin_amdgcn_s_setprio(0); \
  } while(0)

  const unsigned short* As0 = smem;
  const unsigned short* Bs0 = smem + 32768;
  const unsigned short* As1 = smem + 16384;
  const unsigned short* Bs1 = smem + 32768 + 16384;

  STAGE_A(0, 0); STAGE_B(0, 0);
  STAGE_A(1, 1); STAGE_B(1, 1);
  VMW4(); BAR();

  for (int i = 0; i < 8; ++i){
    SUBPH(As0, Bs0, 0);
    SUBPH(As0, Bs0, 1);
    BAR();
    if (i < 7){
      STAGE_A(0, 2*i + 2);
      VMW2(); BAR();
      SUBPH(As1, Bs1, 0);
      STAGE_B(0, 2*i + 2);
      SUBPH(As1, Bs1, 1);
      BAR();
      STAGE_A(1, 2*i + 3);
      STAGE_B(1, 2*i + 3);
      VMW4(); BAR();
    } else {
      VMW0(); BAR();
      SUBPH(As1, Bs1, 0);
      SUBPH(As1, Bs1, 1);
    }
  }

  const int b = m0 >> 11;        // S = 2048
  float psv[4], vav[4];
  #pragma unroll
  for (int ni = 0; ni < 4; ++ni){
    int n = n0 + wc*64 + ni*16 + lr;
    psv[ni] = ps[b*1024 + n] + Ua_b[n];
    vav[ni] = va[n];
  }
  #pragma unroll
  for (int mi = 0; mi < 4; ++mi){
    float p0=0.f,p1=0.f,p2=0.f,p3=0.f;
    #pragma unroll
    for (int ni = 0; ni < 4; ++ni){
      p0 += vav[ni]*fast_tanh(acc[mi][ni][0] + psv[ni]);
      p1 += vav[ni]*fast_tanh(acc[mi][ni][1] + psv[ni]);
      p2 += vav[ni]*fast_tanh(acc[mi][ni][2] + psv[ni]);
      p3 += vav[ni]*fast_tanh(acc[mi][ni][3] + psv[ni]);
    }
    #pragma unroll
    for (int off = 1; off < 16; off <<= 1){
      p0 += __shfl_xor(p0, off);
      p1 += __shfl_xor(p1, off);
      p2 += __shfl_xor(p2, off);
      p3 += __shfl_xor(p3, off);
    }
    if (lr == 0){
      int rg = m0 + wr*64 + mi*16 + lk*4;
      int slot = wgn*4 + wc;
      part[(size_t)rg*16 + slot]     = p0;
      part[(size_t)(rg+1)*16 + slot] = p1;
      part[(size_t)(rg+2)*16 + slot] = p2;
      part[(size_t)(rg+3)*16 + slot] = p3;
    }
  }
#undef SUBPH
}

// ---- fallback f32-staging proje (used only if ws too small for enc_bf) ----
__global__ __launch_bounds__(256,2) void k_proje_f32(
    const float* __restrict__ A,
    const unsigned short* __restrict__ Bw,
    const float* __restrict__ ps,
    const float* __restrict__ Ua_b,
    const float* __restrict__ va,
    float* __restrict__ part)
{
  __shared__ unsigned char sm[32768];
  const int t = threadIdx.x;
  const int lane = t & 63, wid = t >> 6;
  const int lr = lane & 15, lk = lane >> 4;
  int bid = blockIdx.x;
  int L = (bid & 7) * 1024 + (bid >> 3);
  const int wgm = L >> 3, wgn = L & 7;
  const int m0 = wgm * 128, n0 = wgn * 128;
  const int wm = wid >> 1, wn = wid & 1;

  f32x4 acc[4][4] = {};
  const int row2 = t >> 1, half = t & 1;
  const float* aSrc = A + (size_t)(m0 + row2) * 1024 + half * 32;
  const unsigned short* bSrc = Bw + (size_t)(n0 + row2) * 1024 + half * 32;
  unsigned char* Al = sm;
  unsigned char* Bl = sm + 16384;
  const int swzr = row2 & 7;

  for (int kt = 0; kt < 16; ++kt){
    __syncthreads();
    #pragma unroll
    for (int c = 0; c < 4; ++c){
      float4 f0 = *(const float4*)(aSrc + kt*64 + c*8);
      float4 f1 = *(const float4*)(aSrc + kt*64 + c*8 + 4);
      union { unsigned u[4]; s16x8 v; } p;
      p.u[0]=cvt2(f0.x,f0.y); p.u[1]=cvt2(f0.z,f0.w);
      p.u[2]=cvt2(f1.x,f1.y); p.u[3]=cvt2(f1.z,f1.w);
      int ch = half*4 + c;
      *(s16x8*)(Al + row2*128 + ((ch ^ swzr)*16)) = p.v;
    }
    #pragma unroll
    for (int c = 0; c < 4; ++c){
      s16x8 v = *(const s16x8*)(bSrc + kt*64 + (half*4 + c)*8);
      *(s16x8*)(Bl + row2*128 + (((half*4+c) ^ swzr)*16)) = v;
    }
    __syncthreads();
    #pragma unroll
    for (int ks = 0; ks < 2; ++ks){
      s16x8 af[4], bfr[4];
      #pragma unroll
      for (int mi = 0; mi < 4; ++mi){
        int r = wm*64 + mi*16 + lr;
        af[mi] = *(const s16x8*)(Al + r*128 + (((ks*4+lk) ^ (lr&7))*16));
      }
      #pragma unroll
      for (int ni = 0; ni < 4; ++ni){
        int r = wn*64 + ni*16 + lr;
        bfr[ni] = *(const s16x8*)(Bl + r*128 + (((ks*4+lk) ^ (lr&7))*16));
      }
      #pragma unroll
      for (int mi = 0; mi < 4; ++mi)
        #pragma unroll
        for (int ni = 0; ni < 4; ++ni)
          acc[mi][ni] = __builtin_amdgcn_mfma_f32_16x16x32_bf16(af[mi], bfr[ni], acc[mi][ni], 0,0,0);
    }
  }
  const int b = m0 >> 11;
  float psv[4], vav[4];
  #pragma unroll
  for (int ni = 0; ni < 4; ++ni){
    int n = n0 + wn*64 + ni*16 + lr;
    psv[ni] = ps[b*1024 + n] + Ua_b[n];
    vav[ni] = va[n];
  }
  #pragma unroll
  for (int mi = 0; mi < 4; ++mi){
    float p0=0.f,p1=0.f,p2=0.f,p3=0.f;
    #pragma unroll
    for (int ni = 0; ni < 4; ++ni){
      p0 += vav[ni]*fast_tanh(acc[mi][ni][0] + psv[ni]);
      p1 += vav[ni]*fast_tanh(acc[mi][ni][1] + psv[ni]);
      p2 += vav[ni]*fast_tanh(acc[mi][ni][2] + psv[ni]);
      p3 += vav[ni]*fast_tanh(acc[mi][ni][3] + psv[ni]);
    }
    #pragma unroll
    for (int off = 1; off < 16; off <<= 1){
      p0 += __shfl_xor(p0, off);
      p1 += __shfl_xor(p1, off);
      p2 += __shfl_xor(p2, off);
      p3 += __shfl_xor(p3, off);
    }
    if (lr == 0){
      int rg = m0 + wm*64 + mi*16 + lk*4;
      int slot = wgn*2 + wn;
      part[(size_t)rg*16 + slot]     = p0;
      part[(size_t)(rg+1)*16 + slot] = p1;
      part[(size_t)(rg+2)*16 + slot] = p2;
      part[(size_t)(rg+3)*16 + slot] = p3;
    }
  }
}

// ---- skinny GEMM (f32 A): C(64 x N) = A(64 x K) @ [B1|B2]^T + biases ----
__global__ __launch_bounds__(256,2) void k_gemm64(
    const float* __restrict__ A,
    const float* __restrict__ B1,
    const float* __restrict__ B2,
    const float* __restrict__ bias1,
    const float* __restrict__ bias2,
    float* __restrict__ C, int ldC,
    int N, int K, int K1)
{
  __shared__ unsigned char sm[16384];
  const int t = threadIdx.x;
  const int lane = t & 63, wid = t >> 6;
  const int lr = lane & 15, lk = lane >> 4;
  const int n0 = blockIdx.x * 64;
  f32x4 acc[4] = {};
  const int row = t >> 2, seg = t & 3;
  unsigned char* Al = sm;
  unsigned char* Bl = sm + 8192;
  const int swzr = row & 7;
  const int K2 = K - K1;

  for (int k0 = 0; k0 < K; k0 += 64){
    __syncthreads();
    {
      const float* s = A + (size_t)row*K + k0 + seg*16;
      #pragma unroll
      for (int c = 0; c < 2; ++c){
        float4 f0 = *(const float4*)(s + c*8);
        float4 f1 = *(const float4*)(s + c*8 + 4);
        union { unsigned u[4]; s16x8 v; } p;
        p.u[0]=cvt2(f0.x,f0.y); p.u[1]=cvt2(f0.z,f0.w);
        p.u[2]=cvt2(f1.x,f1.y); p.u[3]=cvt2(f1.z,f1.w);
        *(s16x8*)(Al + row*128 + (((seg*2+c) ^ swzr)*16)) = p.v;
      }
    }
    {
      int n = n0 + row;
      #pragma unroll
      for (int c = 0; c < 2; ++c){
        union { unsigned u[4]; s16x8 v; } p;
        if (n < N){
          int k = k0 + seg*16 + c*8;
          const float* s;
          if (k < K1) s = B1 + (size_t)n*K1 + k;
          else        s = B2 + (size_t)n*K2 + (k - K1);
          float4 f0 = *(const float4*)(s);
          float4 f1 = *(const float4*)(s + 4);
          p.u[0]=cvt2(f0.x,f0.y); p.u[1]=cvt2(f0.z,f0.w);
          p.u[2]=cvt2(f1.x,f1.y); p.u[3]=cvt2(f1.z,f1.w);
        } else {
          p.u[0]=0u; p.u[1]=0u; p.u[2]=0u; p.u[3]=0u;
        }
        *(s16x8*)(Bl + row*128 + (((seg*2+c) ^ swzr)*16)) = p.v;
      }
    }
    __syncthreads();
    #pragma unroll
    for (int ks = 0; ks < 2; ++ks){
      s16x8 bfr = *(const s16x8*)(Bl + (wid*16+lr)*128 + (((ks*4+lk) ^ (lr&7))*16));
      #pragma unroll
      for (int mi = 0; mi < 4; ++mi){
        s16x8 af = *(const s16x8*)(Al + (mi*16+lr)*128 + (((ks*4+lk) ^ (lr&7))*16));
        acc[mi] = __builtin_amdgcn_mfma_f32_16x16x32_bf16(af, bfr, acc[mi], 0,0,0);
      }
    }
  }
  int n = n0 + wid*16 + lr;
  if (n < N){
    float bv = (bias1 ? bias1[n] : 0.f) + (bias2 ? bias2[n] : 0.f);
    #pragma unroll
    for (int mi = 0; mi < 4; ++mi){
      #pragma unroll
      for (int r = 0; r < 4; ++r){
        C[(size_t)(mi*16 + lk*4 + r)*ldC + n] = acc[mi][r] + bv;
      }
    }
  }
}

// ---- skinny GEMM (bf16 A): C(64 x N) = Abf(64 x K) @ [B1|B2]^T + biases ----
// A pre-converted bf16: stage = pure vector copy, no cvt. 3 blocks/CU.
__global__ __launch_bounds__(256,3) void k_gemm64b(
    const unsigned short* __restrict__ A,
    const float* __restrict__ B1,
    const float* __restrict__ B2,
    const float* __restrict__ bias1,
    const float* __restrict__ bias2,
    float* __restrict__ C, int ldC,
    int N, int K, int K1)
{
  __shared__ unsigned char sm[16384];
  const int t = threadIdx.x;
  const int lane = t & 63, wid = t >> 6;
  const int lr = lane & 15, lk = lane >> 4;
  const int n0 = blockIdx.x * 64;
  f32x4 acc[4] = {};
  const int row = t >> 2, seg = t & 3;
  unsigned char* Al = sm;
  unsigned char* Bl = sm + 8192;
  const int swzr = row & 7;
  const int K2 = K - K1;

  for (int k0 = 0; k0 < K; k0 += 64){
    __syncthreads();
    {
      const unsigned short* s = A + (size_t)row*K + k0 + seg*16;
      #pragma unroll
      for (int c = 0; c < 2; ++c){
        s16x8 v = *(const s16x8*)(s + c*8);
        *(s16x8*)(Al + row*128 + (((seg*2+c) ^ swzr)*16)) = v;
      }
    }
    {
      int n = n0 + row;
      #pragma unroll
      for (int c = 0; c < 2; ++c){
        union { unsigned u[4]; s16x8 v; } p;
        if (n < N){
          int k = k0 + seg*16 + c*8;
          const float* s;
          if (k < K1) s = B1 + (size_t)n*K1 + k;
          else        s = B2 + (size_t)n*K2 + (k - K1);
          float4 f0 = *(const float4*)(s);
          float4 f1 = *(const float4*)(s + 4);
          p.u[0]=cvt2(f0.x,f0.y); p.u[1]=cvt2(f0.z,f0.w);
          p.u[2]=cvt2(f1.x,f1.y); p.u[3]=cvt2(f1.z,f1.w);
        } else {
          p.u[0]=0u; p.u[1]=0u; p.u[2]=0u; p.u[3]=0u;
        }
        *(s16x8*)(Bl + row*128 + (((seg*2+c) ^ swzr)*16)) = p.v;
      }
    }
    __syncthreads();
    #pragma unroll
    for (int ks = 0; ks < 2; ++ks){
      s16x8 bfr = *(const s16x8*)(Bl + (wid*16+lr)*128 + (((ks*4+lk) ^ (lr&7))*16));
      #pragma unroll
      for (int mi = 0; mi < 4; ++mi){
        s16x8 af = *(const s16x8*)(Al + (mi*16+lr)*128 + (((ks*4+lk) ^ (lr&7))*16));
        acc[mi] = __builtin_amdgcn_mfma_f32_16x16x32_bf16(af, bfr, acc[mi], 0,0,0);
      }
    }
  }
  int n = n0 + wid*16 + lr;
  if (n < N){
    float bv = (bias1 ? bias1[n] : 0.f) + (bias2 ? bias2[n] : 0.f);
    #pragma unroll
    for (int mi = 0; mi < 4; ++mi){
      #pragma unroll
      for (int r = 0; r < 4; ++r){
        C[(size_t)(mi*16 + lk*4 + r)*ldC + n] = acc[mi][r] + bv;
      }
    }
  }
}

// ---- softmax over S per batch ----
__global__ __launch_bounds__(256) void k_softmax(const float* __restrict__ part,
                                                 const float* __restrict__ va_b,
                                                 float* __restrict__ attn){
  __shared__ float sc[2048];
  __shared__ float red[8];
  const int b = blockIdx.x, t = threadIdx.x;
  float vb = va_b[0];
  float lmax = -1e30f;
  #pragma unroll
  for (int j = 0; j < 8; ++j){
    int s = t + j*256;
    const float* p = part + ((size_t)b*2048 + s)*16;
    float v = vb;
    #pragma unroll
    for (int i = 0; i < 16; ++i) v += p[i];
    sc[s] = v;
    lmax = fmaxf(lmax, v);
  }
  for (int off = 32; off; off >>= 1) lmax = fmaxf(lmax, __shfl_xor(lmax, off));
  if ((t&63)==0) red[t>>6] = lmax;
  __syncthreads();
  float m = fmaxf(fmaxf(red[0],red[1]),fmaxf(red[2],red[3]));
  float lsum = 0.f;
  #pragma unroll
  for (int j = 0; j < 8; ++j){
    int s = t + j*256;
    float e = __expf(sc[s]-m);
    sc[s] = e; lsum += e;
  }
  for (int off = 32; off; off >>= 1) lsum += __shfl_xor(lsum, off);
  if ((t&63)==0) red[4 + (t>>6)] = lsum;
  __syncthreads();
  float inv = 1.f/(red[4]+red[5]+red[6]+red[7]);
  #pragma unroll
  for (int j = 0; j < 8; ++j){
    int s = t + j*256;
    attn[(size_t)b*2048+s] = sc[s]*inv;
  }
}

// ---- context partials from bf16 enc: 16 chunks of 128 ----
__global__ __launch_bounds__(256) void k_context_bf(const float* __restrict__ attn,
                                                    const unsigned short* __restrict__ encb,
                                                    float* __restrict__ ctxp){
  const int b = blockIdx.x >> 4, scid = blockIdx.x & 15;
  const int t = threadIdx.x;
  float a0=0.f,a1=0.f,a2=0.f,a3=0.f;
  const unsigned short* e = encb + ((size_t)b*2048 + scid*128)*1024 + t*4;
  const float* at = attn + (size_t)b*2048 + scid*128;
  #pragma unroll 4
  for (int s = 0; s < 128; ++s){
    float a = at[s];
    ushort4 v = *(const ushort4*)(e + (size_t)s*1024);
    a0 += a*bf2f(v.x); a1 += a*bf2f(v.y); a2 += a*bf2f(v.z); a3 += a*bf2f(v.w);
  }
  float4 o; o.x=a0; o.y=a1; o.z=a2; o.w=a3;
  *(float4*)(ctxp + ((size_t)scid*64 + b)*1024 + t*4) = o;
}

// ---- context partials from f32 enc (fallback), 16 chunks ----
__global__ __launch_bounds__(256) void k_context_f32(const float* __restrict__ attn,
                                                     const float* __restrict__ enc,
                                                     float* __restrict__ ctxp){
  const int b = blockIdx.x >> 4, scid = blockIdx.x & 15;
  const int t = threadIdx.x;
  float a0=0.f,a1=0.f,a2=0.f,a3=0.f;
  const float* e = enc + ((size_t)b*2048 + scid*128)*1024;
  const float* at = attn + (size_t)b*2048 + scid*128;
  for (int s = 0; s < 128; ++s){
    float a = at[s];
    const float* er = e + (size_t)s*1024;
    a0 += a*er[t]; a1 += a*er[t+256]; a2 += a*er[t+512]; a3 += a*er[t+768];
  }
  float* o = ctxp + ((size_t)scid*64 + b)*1024;
  o[t]=a0; o[t+256]=a1; o[t+512]=a2; o[t+768]=a3;
}

// ---- build lstm_bf [64][2560] bf16 = [emb | ctx reduce(16) | hidden] ----
__global__ __launch_bounds__(256) void k_build(const int* __restrict__ x,
                                               const float* __restrict__ emb,
                                               const float* __restrict__ ctxp,
                                               const float* __restrict__ hidden,
                                               unsigned short* __restrict__ lstm){
  const int b = blockIdx.x, t = threadIdx.x;
  int xe = x[b];
  for (int col = t; col < 2560; col += 256){
    float v;
    if (col < 512) v = emb[(size_t)xe*512 + col];
    else if (col < 1536){
      int h = col - 512;
      v = 0.f;
      #pragma unroll
      for (int i = 0; i < 16; ++i) v += ctxp[((size_t)i*64 + b)*1024 + h];
    } else v = hidden[(size_t)b*1024 + (col-1536)];
    lstm[(size_t)b*2560 + col] = f2bf(v);
  }
}

// ---- LSTM pointwise (+ bf16 copy of h_new for FC) ----
__global__ __launch_bounds__(256) void k_lstm(const float* __restrict__ gates,
                                              const float* __restrict__ cell,
                                              float* __restrict__ out,
                                              unsigned short* __restrict__ hbf){
  int idx = blockIdx.x*256 + threadIdx.x;  // 0..65535
  int b = idx >> 10, h = idx & 1023;
  const float* g = gates + (size_t)b*4096;
  float gi = fast_sig(g[h]);
  float gf = fast_sig(g[h+1024]);
  float gg = fast_tanh(g[h+2048]);
  float go = fast_sig(g[h+3072]);
  float c  = gf*cell[idx] + gi*gg;
  float hn = go*fast_tanh(c);
  out[(size_t)V_*64 + idx]         = hn;   // h_new
  out[(size_t)V_*64 + 65536 + idx] = c;    // c_new
  hbf[idx] = f2bf(hn);
}

extern "C" void kernel_launch(void* const* d_in, const int* in_sizes, int n_in,
                              void* d_out, int out_size, void* d_ws, size_t ws_size,
                              hipStream_t stream){
  const int*   x     = (const int*)d_in[0];
  const float* hidden= (const float*)d_in[1];
  const float* cell  = (const float*)d_in[2];
  const float* enc   = (const float*)d_in[3];
  const float* emb   = (const float*)d_in[4];
  const float* Wa_w  = (const float*)d_in[5];
  const float* Wa_b  = (const float*)d_in[6];
  const float* Ua_w  = (const float*)d_in[7];
  const float* Ua_b  = (const float*)d_in[8];
  const float* va_w  = (const float*)d_in[9];
  const float* va_b  = (const float*)d_in[10];
  const float* Wih   = (const float*)d_in[11];
  const float* Whh   = (const float*)d_in[12];
  const float* bih   = (const float*)d_in[13];
  const float* bhh   = (const float*)d_in[14];
  const float* fc_w  = (const float*)d_in[15];
  const float* fc_b  = (const float*)d_in[16];
  float* out = (float*)d_out;
  char* ws = (char*)d_ws;
  unsigned short* ua_bf = (unsigned short*)(ws + 0);        // 2 MB
  float* ps    = (float*)(ws + 2097152);                    // 256 KB
  float* attn  = (float*)(ws + 2359296);                    // 512 KB
  unsigned short* lstm_bf = (unsigned short*)(ws + 2883584);// 320 KB
  float* gates = (float*)(ws + 3538944);                    // 1 MB
  float* part  = (float*)(ws + 6684672);                    // 8 MB [6684672, 15073280)
  // ctxp aliases part's upper half: part is dead after k_softmax, before k_context runs
  float* ctxp  = (float*)(ws + 10878976);                   // 4 MB [10878976, 15073280)
  unsigned short* h_bf = (unsigned short*)(ws + 15073280);  // 128 KB
  unsigned short* enc_bf = (unsigned short*)(ws + 16777216);// 256 MB
  const size_t REQ = 16777216u + 268435456u;

  hipLaunchKernelGGL(k_cvt_bf16, dim3(1024), dim3(256), 0, stream, Ua_w, ua_bf, 1048576);
  hipLaunchKernelGGL(k_gemm64, dim3(16), dim3(256), 0, stream,
                     hidden, Wa_w, nullptr, Wa_b, nullptr, ps, 1024, 1024, 1024, 1024);
  if (ws_size >= REQ){
    hipLaunchKernelGGL(k_cvt_enc, dim3(8192), dim3(256), 0, stream, enc, enc_bf);
    hipLaunchKernelGGL(k_proje256, dim3(2048), dim3(1024), 131072, stream,
                       enc_bf, ua_bf, ps, Ua_b, va_w, part);
    hipLaunchKernelGGL(k_softmax, dim3(64), dim3(256), 0, stream, part, va_b, attn);
    hipLaunchKernelGGL(k_context_bf, dim3(1024), dim3(256), 0, stream, attn, enc_bf, ctxp);
  } else {
    hipLaunchKernelGGL(k_proje_f32, dim3(8192), dim3(256), 0, stream,
                       enc, ua_bf, ps, Ua_b, va_w, part);
    hipLaunchKernelGGL(k_softmax, dim3(64), dim3(256), 0, stream, part, va_b, attn);
    hipLaunchKernelGGL(k_context_f32, dim3(1024), dim3(256), 0, stream, attn, enc, ctxp);
  }
  hipLaunchKernelGGL(k_build, dim3(64), dim3(256), 0, stream, x, emb, ctxp, hidden, lstm_bf);
  hipLaunchKernelGGL(k_gemm64b, dim3(64), dim3(256), 0, stream,
                     lstm_bf, Wih, Whh, bih, bhh, gates, 4096, 4096, 2560, 1536);
  hipLaunchKernelGGL(k_lstm, dim3(256), dim3(256), 0, stream, gates, cell, out, h_bf);
  hipLaunchKernelGGL(k_gemm64b, dim3(786), dim3(256), 0, stream,
                     h_bf, fc_w, nullptr, fc_b, nullptr, out, V_, V_, 1024, 1024);
}